// Round 4
// baseline (363.224 us; speedup 1.0000x reference)
//
#include <hip/hip_runtime.h>
#include <math.h>

// VectorExpansion: out[l, p, n] = sin(pi*x*n)/max(r,eps) * fc(r) * sqrt(2/rc) * x^l
// x = r/rc, rc=5, n=1..8, l=0..3.  fp32 in / fp32 out.
//
// R9 (post-mortem R8: dense NT stores cut kernel ~199->~111us, confirming R7's
// 1.94x WRITE amplification came from NT flushing partial sectors with no
// cross-instruction merge -> NT bypasses the L2 writeback path. Residual
// ~111us over a 294MB floor = 2.7 TB/s, vs 6.4 TB/s the harness's plain-store
// fill kernel sustains with FETCH~0 (no RFO). Theory: the NT path itself caps
// store BW.):
//   Clean A/B vs R7: IDENTICAL 1-thread-per-pair structure, PLAIN stores.
//   The writeback L2 merges each lane's two adjacent 16B stores into full
//   lines, so the 32B/lane-stride pattern writes each line back exactly once
//   (prediction: WRITE_SIZE 508,700 KB -> ~262,200 KB floor). One thread per
//   pair also keeps gather/TA address pressure at half of R8's.
//   Traffic floor: 256 MiB write + ~26 MB read -> ~47 us at 6.3 TB/s.

#define RC_INV 0.2f
#define NORM 0.6324555320336759f  /* sqrt(2/5) */

typedef float f32x4 __attribute__((ext_vector_type(4)));

__global__ __launch_bounds__(256) void ve_dense(
    const float* __restrict__ positions,        // [N,3] fp32
    const float* __restrict__ cells,            // [S,3,3] fp32
    const int* __restrict__ cell_shifts,        // [P,3]
    const int* __restrict__ pairs,              // [P,2]
    const int* __restrict__ structure_pairs,    // [P]
    const int* __restrict__ structure_offsets,  // [S]
    f32x4* __restrict__ out4,                   // [4,P,8] fp32 viewed as f32x4
    int P)
{
    const int p = blockIdx.x * blockDim.x + threadIdx.x;
    if (p >= P) return;

    const int s   = structure_pairs[p];
    const int off = structure_offsets[s];       // S=32 table, L1-resident
    const int2 pr = ((const int2*)pairs)[p];
    const int ia = 3 * (off + pr.x);
    const int ja = 3 * (off + pr.y);

    const float shx = (float)cell_shifts[3*p + 0];
    const float shy = (float)cell_shifts[3*p + 1];
    const float shz = (float)cell_shifts[3*p + 2];

    const float* C = cells + 9*s;               // row-major [c][d], L1-resident
    const float vx = positions[ja+0] - positions[ia+0] + shx*C[0] + shy*C[3] + shz*C[6];
    const float vy = positions[ja+1] - positions[ia+1] + shx*C[1] + shy*C[4] + shz*C[7];
    const float vz = positions[ja+2] - positions[ia+2] + shx*C[2] + shy*C[5] + shz*C[8];

    const float d2 = vx*vx + vy*vy + vz*vz + 1e-12f;
    const float r  = __builtin_amdgcn_sqrtf(d2);
    const float x  = r * RC_INV;
    const float xa = fminf(x, 1.0f);            // clamp for trig; pref zeroes x>=1 lanes

    // sin(pi*xa), cos(pi*xa) via HW trig (arg in revolutions; xa in [0,1] so
    // 0.5*xa in [0,0.5] needs no range reduction).
    const float s1 = __builtin_amdgcn_sinf(0.5f * xa);
    const float c1 = __builtin_amdgcn_cosf(0.5f * xa);
    const float fc = 0.5f * (c1 + 1.0f);
    // Exact 0 outside cutoff (matches reference's where()) -> zero rows stream
    // through the same stores; no branch, no divergence.
    const float pref = (x < 1.0f) ? fc * NORM * __builtin_amdgcn_rcpf(r) : 0.0f;

    // sin(n*pi*xa) by Chebyshev recurrence: s_{n+1} = 2*cos(pi*xa)*s_n - s_{n-1}
    float b[8];
    {
        float sm1 = 0.0f, sn = s1;
        const float twoc = 2.0f * c1;
        #pragma unroll
        for (int n = 0; n < 8; ++n) {
            b[n] = pref * sn;
            const float nxt = twoc * sn - sm1;
            sm1 = sn; sn = nxt;
        }
    }

    // out flat (l,p,n) = l*P*8 + p*8 + n  ->  f32x4 slot (l*P+p)*2 + {0,1}
    // PLAIN stores: per wave per l the 2 instrs cover one contiguous 2 KB
    // region; the writeback L2 merges them into full lines (no NT bypass).
    float xl = 1.0f;
    #pragma unroll
    for (int l = 0; l < 4; ++l) {
        const long long base = 2LL * (1LL*l*P + p);
        f32x4 lo = { b[0]*xl, b[1]*xl, b[2]*xl, b[3]*xl };
        f32x4 hi = { b[4]*xl, b[5]*xl, b[6]*xl, b[7]*xl };
        out4[base + 0] = lo;
        out4[base + 1] = hi;
        xl *= xa;                               // x^l; pref==0 already zeroes x>=1 lanes
    }
}

extern "C" void kernel_launch(void* const* d_in, const int* in_sizes, int n_in,
                              void* d_out, int out_size, void* d_ws, size_t ws_size,
                              hipStream_t stream) {
    const float* positions         = (const float*)d_in[0];
    const float* cells             = (const float*)d_in[1];
    const int*   cell_shifts       = (const int*)d_in[3];
    const int*   pairs             = (const int*)d_in[5];
    const int*   structure_pairs   = (const int*)d_in[7];
    const int*   structure_offsets = (const int*)d_in[8];

    const int P = in_sizes[7];          // structure_pairs is [P]
    const int block = 256;

    ve_dense<<<(P + block - 1) / block, block, 0, stream>>>(
        positions, cells, cell_shifts, pairs,
        structure_pairs, structure_offsets, (f32x4*)d_out, P);
}

// Round 5
// 361.841 us; speedup vs baseline: 1.0038x; 1.0038x over previous
//
#include <hip/hip_runtime.h>
#include <math.h>

// VectorExpansion: out[l, p, n] = sin(pi*x*n)/max(r,eps) * fc(r) * sqrt(2/rc) * x^l
// x = r/rc, rc=5, n=1..8, l=0..3.  fp32 in / fp32 out.
//
// R10 (post-mortem R8/R9: NT-dense ~111us, plain-strided ~123us, NT-strided
// 199us. All structures cap at ~2.3-2.7 TB/s vs the 6.4 TB/s the harness's
// own fillBufferAligned sustains in the same timed region. Write pattern was
// a 2x lever (R7's 1.94x WRITE amplification, fixed), but the residual cap is
// NOT store width/sectors. Remaining structural difference vs fill: fill is a
// low-occupancy grid-stride LOOP (10% occ, 6.4 TB/s) -> always has
// independent stores in flight; ours was 4M one-shot threads each running a
// dependent gather->latency->compute->store chain with zero cross-pair ILP,
// all waves parked on vmcnt simultaneously.):
//   GRID-STRIDE PERSISTENT kernel, fill-shaped: 1024 blocks x 256 threads,
//   ~16 iterations/thread, unroll 2 so the compiler software-pipelines the
//   next iteration's independent pair-stream loads under the current
//   iteration's stores. Dense store mapping kept from R8 (2 lanes per pair,
//   h=gid&1 -> consecutive lanes write consecutive 16B slots, every store
//   instruction a full-sector 1KB block) but PLAIN stores (writeback L2,
//   no NT flush quirks; full-line streaming doesn't RFO per fill's FETCH~0).
//   Traffic floor: 256 MiB write + ~48 MB read -> ~48 us at 6.4 TB/s.

#define RC_INV 0.2f
#define NORM 0.6324555320336759f  /* sqrt(2/5) */

typedef float f32x4 __attribute__((ext_vector_type(4)));

__global__ __launch_bounds__(256) void ve_loop(
    const float* __restrict__ positions,        // [N,3] fp32
    const float* __restrict__ cells,            // [S,3,3] fp32
    const int* __restrict__ cell_shifts,        // [P,3]
    const int* __restrict__ pairs,              // [P,2]
    const int* __restrict__ structure_pairs,    // [P]
    const int* __restrict__ structure_offsets,  // [S]
    f32x4* __restrict__ out4,                   // [4,P,8] fp32 viewed as f32x4
    int P)
{
    const long long T = (long long)gridDim.x * blockDim.x;   // total threads
    const long long n = 2LL * P;                             // 2 lanes per pair

    #pragma unroll 2
    for (long long gid = (long long)blockIdx.x * blockDim.x + threadIdx.x;
         gid < n; gid += T) {
        const int p = (int)(gid >> 1);          // pair index
        const int h = (int)(gid & 1);           // which f32x4 half (n 0-3 / 4-7)

        const int s   = structure_pairs[p];
        const int off = structure_offsets[s];   // S=32 table, L1-resident
        const int2 pr = ((const int2*)pairs)[p];
        const int ia = 3 * (off + pr.x);
        const int ja = 3 * (off + pr.y);

        const float shx = (float)cell_shifts[3*p + 0];
        const float shy = (float)cell_shifts[3*p + 1];
        const float shz = (float)cell_shifts[3*p + 2];

        const float* C = cells + 9*s;           // row-major [c][d], L1-resident
        const float vx = positions[ja+0] - positions[ia+0] + shx*C[0] + shy*C[3] + shz*C[6];
        const float vy = positions[ja+1] - positions[ia+1] + shx*C[1] + shy*C[4] + shz*C[7];
        const float vz = positions[ja+2] - positions[ia+2] + shx*C[2] + shy*C[5] + shz*C[8];

        const float d2 = vx*vx + vy*vy + vz*vz + 1e-12f;
        const float r  = __builtin_amdgcn_sqrtf(d2);
        const float x  = r * RC_INV;
        const float xa = fminf(x, 1.0f);        // clamp for trig; pref zeroes x>=1

        // sin(pi*xa), cos(pi*xa) via HW trig (arg in revolutions; 0.5*xa in
        // [0,0.5] needs no range reduction).
        const float s1 = __builtin_amdgcn_sinf(0.5f * xa);
        const float c1 = __builtin_amdgcn_cosf(0.5f * xa);
        const float fcut = 0.5f * (c1 + 1.0f);
        // Exact 0 outside cutoff (matches reference's where()).
        const float pref = (x < 1.0f) ? fcut * NORM * __builtin_amdgcn_rcpf(r) : 0.0f;

        // sin(n*pi*xa) by Chebyshev: s_{n+1} = 2*cos(pi*xa)*s_n - s_{n-1}
        float b[8];
        {
            float sm1 = 0.0f, sn = s1;
            const float twoc = 2.0f * c1;
            #pragma unroll
            for (int nn = 0; nn < 8; ++nn) {
                b[nn] = pref * sn;
                const float nxt = twoc * sn - sm1;
                sm1 = sn; sn = nxt;
            }
        }

        // This thread's half (static indexing only — no scratch).
        const float e0 = h ? b[4] : b[0];
        const float e1 = h ? b[5] : b[1];
        const float e2 = h ? b[6] : b[2];
        const float e3 = h ? b[7] : b[3];

        // out flat (l,p,n): f32x4 slot = 2*l*P + 2*p + h = 2*l*P + gid.
        // Consecutive lanes -> consecutive 16B slots: dense 1KB per instr.
        float xl = 1.0f;
        #pragma unroll
        for (int l = 0; l < 4; ++l) {
            f32x4 v = { e0*xl, e1*xl, e2*xl, e3*xl };
            out4[2LL * l * P + gid] = v;
            xl *= xa;                           // x^l; pref==0 zeroes x>=1 lanes
        }
    }
}

extern "C" void kernel_launch(void* const* d_in, const int* in_sizes, int n_in,
                              void* d_out, int out_size, void* d_ws, size_t ws_size,
                              hipStream_t stream) {
    const float* positions         = (const float*)d_in[0];
    const float* cells             = (const float*)d_in[1];
    const int*   cell_shifts       = (const int*)d_in[3];
    const int*   pairs             = (const int*)d_in[5];
    const int*   structure_pairs   = (const int*)d_in[7];
    const int*   structure_offsets = (const int*)d_in[8];

    const int P = in_sizes[7];          // structure_pairs is [P]
    const int block = 256;
    const int nblk  = 1024;             // fill-kernel-shaped: few blocks, deep loop

    ve_loop<<<nblk, block, 0, stream>>>(
        positions, cells, cell_shifts, pairs,
        structure_pairs, structure_offsets, (f32x4*)d_out, P);
}

// Round 7
// 302.284 us; speedup vs baseline: 1.2016x; 1.1970x over previous
//
#include <hip/hip_runtime.h>
#include <math.h>

// VectorExpansion: out[l, p, n] = sin(pi*x*n)/max(r,eps) * fc(r) * sqrt(2/rc) * x^l
// x = r/rc, rc=5, n=1..8, l=0..3.  fp32 in / fp32 out.
//
// R12 = R11 resubmitted verbatim (R11 bench was an infra failure: "MI355X
// container failed twice" — no compile/correctness/counter signal).
//
// R11 rationale (post-mortem R8-R10: three structurally different FUSED
// kernels — one-shot strided-plain, one-shot dense-NT, grid-stride
// dense-plain — all cap at ~2.6 TB/s (~111-123us) while pure-write fill
// dispatches in the same timed region hit 6.3 TB/s. Mixed read+write traffic
// is the cap, not store pattern/occupancy/loop shape. Control point: the R5
// SPLIT measured ~92us of kernels (331.9 harness) — faster than every fused
// variant. Conclusion: phase-separate the streams; tune each phase.):
//   Kernel 1: grid-stride loop zero-fill (rocclr-fill-shaped: 1024x256, deep
//             loop, plain full-line f32x4 stores, no RFO) -> 268 MB @ ~6.3
//             TB/s ~= 43us. (R5's fill was one-shot thread-per-slot.)
//   Kernel 2: sparse pair pass, 1 thread/pair one-shot: read 48 MB pair
//             stream, compute r; ~97% of lanes exit before trig/stores; the
//             ~3% in-cutoff lanes write their 4x2 f32x4 rows. ~25-35us.

#define RC_INV 0.2f
#define NORM 0.6324555320336759f  /* sqrt(2/5) */

typedef float f32x4 __attribute__((ext_vector_type(4)));

__global__ __launch_bounds__(256) void fill_zero(f32x4* __restrict__ out4, int n4) {
    const int T = gridDim.x * blockDim.x;
    const f32x4 z = {0.f, 0.f, 0.f, 0.f};
    #pragma unroll 4
    for (int i = blockIdx.x * blockDim.x + threadIdx.x; i < n4; i += T)
        out4[i] = z;
}

__global__ __launch_bounds__(256) void ve_sparse(
    const float* __restrict__ positions,        // [N,3] fp32
    const float* __restrict__ cells,            // [S,3,3] fp32
    const int* __restrict__ cell_shifts,        // [P,3]
    const int* __restrict__ pairs,              // [P,2]
    const int* __restrict__ structure_pairs,    // [P]
    const int* __restrict__ structure_offsets,  // [S]
    f32x4* __restrict__ out4,                   // [4,P,8] fp32 (pre-zeroed)
    int P)
{
    const int p = blockIdx.x * blockDim.x + threadIdx.x;
    if (p >= P) return;

    const int s   = structure_pairs[p];
    const int off = structure_offsets[s];       // S=32 table, L1-resident
    const int2 pr = ((const int2*)pairs)[p];
    const int ia = 3 * (off + pr.x);
    const int ja = 3 * (off + pr.y);

    const float shx = (float)cell_shifts[3*p + 0];
    const float shy = (float)cell_shifts[3*p + 1];
    const float shz = (float)cell_shifts[3*p + 2];

    const float* C = cells + 9*s;               // row-major [c][d], L1-resident
    const float vx = positions[ja+0] - positions[ia+0] + shx*C[0] + shy*C[3] + shz*C[6];
    const float vy = positions[ja+1] - positions[ia+1] + shx*C[1] + shy*C[4] + shz*C[7];
    const float vz = positions[ja+2] - positions[ia+2] + shx*C[2] + shy*C[5] + shz*C[8];

    const float d2 = vx*vx + vy*vy + vz*vz + 1e-12f;
    const float r  = __builtin_amdgcn_sqrtf(d2);
    const float x  = r * RC_INV;

    if (x >= 1.0f) return;                      // fc==0 -> row already zeroed by fill

    // sin(pi*x), cos(pi*x) via HW trig (arg in revolutions; x in [0,1) so
    // 0.5*x needs no range reduction).
    const float s1 = __builtin_amdgcn_sinf(0.5f * x);
    const float c1 = __builtin_amdgcn_cosf(0.5f * x);
    const float fc = 0.5f * (c1 + 1.0f);
    const float pref = fc * NORM * __builtin_amdgcn_rcpf(r);

    // sin(n*pi*x) by Chebyshev recurrence: s_{n+1} = 2*cos(pi*x)*s_n - s_{n-1}
    float b[8];
    {
        float sm1 = 0.0f, sn = s1;
        const float twoc = 2.0f * c1;
        #pragma unroll
        for (int n = 0; n < 8; ++n) {
            b[n] = pref * sn;
            const float nxt = twoc * sn - sm1;
            sm1 = sn; sn = nxt;
        }
    }

    // out flat (l,p,n) = l*P*8 + p*8 + n  ->  f32x4 slot (l*P+p)*2 + {0,1}
    float xl = 1.0f;
    #pragma unroll
    for (int l = 0; l < 4; ++l) {
        const long long base = 2LL * (1LL*l*P + p);
        f32x4 lo = { b[0]*xl, b[1]*xl, b[2]*xl, b[3]*xl };
        f32x4 hi = { b[4]*xl, b[5]*xl, b[6]*xl, b[7]*xl };
        out4[base + 0] = lo;
        out4[base + 1] = hi;
        xl *= x;
    }
}

extern "C" void kernel_launch(void* const* d_in, const int* in_sizes, int n_in,
                              void* d_out, int out_size, void* d_ws, size_t ws_size,
                              hipStream_t stream) {
    const float* positions         = (const float*)d_in[0];
    const float* cells             = (const float*)d_in[1];
    const int*   cell_shifts       = (const int*)d_in[3];
    const int*   pairs             = (const int*)d_in[5];
    const int*   structure_pairs   = (const int*)d_in[7];
    const int*   structure_offsets = (const int*)d_in[8];

    const int P = in_sizes[7];          // structure_pairs is [P]
    const int block = 256;

    const int n4 = out_size / 16;       // out_size = 4*P*8*4 bytes, /16 = f32x4 slots
    fill_zero<<<1024, block, 0, stream>>>((f32x4*)d_out, n4);

    ve_sparse<<<(P + block - 1) / block, block, 0, stream>>>(
        positions, cells, cell_shifts, pairs,
        structure_pairs, structure_offsets, (f32x4*)d_out, P);
}

// Round 8
// 300.973 us; speedup vs baseline: 1.2068x; 1.0044x over previous
//
#include <hip/hip_runtime.h>
#include <math.h>

// VectorExpansion: out[l, p, n] = sin(pi*x*n)/max(r,eps) * fc(r) * sqrt(2/rc) * x^l
// x = r/rc, rc=5, n=1..8, l=0..3.  fp32 in / fp32 out.
//
// R13 (post-mortem R12: split structure confirmed at harness 302.3us = new
// best; kernels total ~62us vs ~51us composite floor (268MB fill-write @6.4
// + 48MB pair-read + 8MB scattered write). Fill clones the rocclr fill shape
// that measures 6.3-6.6 TB/s every round -> at rate. Residual slack is the
// sparse pass: 2M one-shot threads, dependent 5-instr scalar load chains
// (cell_shifts at lane-stride 12B = 3 partially-dense loads) -> latency/
// issue-bound ~19us vs ~10us floor.):
//   Kernel 1: grid-stride zero-fill, unchanged.
//   Kernel 2: sparse pass, grid-stride, TWO consecutive pairs per thread,
//             vectorized pair-stream loads (int4 pairs / int2 structure_pairs
//             / 3x int2 cell_shifts = 5 loads per 2 pairs vs 10 scalar),
//             unroll 2 so independent iterations pipeline under gather
//             latency. ~97% of lanes skip trig+stores (row pre-zeroed).

#define RC_INV 0.2f
#define NORM 0.6324555320336759f  /* sqrt(2/5) */

typedef float f32x4 __attribute__((ext_vector_type(4)));

__global__ __launch_bounds__(256) void fill_zero(f32x4* __restrict__ out4, int n4) {
    const int T = gridDim.x * blockDim.x;
    const f32x4 z = {0.f, 0.f, 0.f, 0.f};
    #pragma unroll 4
    for (int i = blockIdx.x * blockDim.x + threadIdx.x; i < n4; i += T)
        out4[i] = z;
}

__device__ __forceinline__ void ve_one(
    const float* __restrict__ positions, const float* __restrict__ cells,
    const int* __restrict__ structure_offsets, f32x4* __restrict__ out4,
    int P, int p, int s, int pi, int pj, int sx, int sy, int sz)
{
    const int off = structure_offsets[s];       // S=32 table, L1-resident
    const int ia = 3 * (off + pi);
    const int ja = 3 * (off + pj);

    const float shx = (float)sx, shy = (float)sy, shz = (float)sz;
    const float* C = cells + 9*s;               // row-major [c][d], L1-resident
    const float vx = positions[ja+0] - positions[ia+0] + shx*C[0] + shy*C[3] + shz*C[6];
    const float vy = positions[ja+1] - positions[ia+1] + shx*C[1] + shy*C[4] + shz*C[7];
    const float vz = positions[ja+2] - positions[ia+2] + shx*C[2] + shy*C[5] + shz*C[8];

    const float d2 = vx*vx + vy*vy + vz*vz + 1e-12f;
    const float r  = __builtin_amdgcn_sqrtf(d2);
    const float x  = r * RC_INV;

    if (x >= 1.0f) return;                      // fc==0 -> row already zeroed

    // sin(pi*x), cos(pi*x) via HW trig (revolutions; 0.5*x in [0,0.5], no
    // range reduction needed).
    const float s1 = __builtin_amdgcn_sinf(0.5f * x);
    const float c1 = __builtin_amdgcn_cosf(0.5f * x);
    const float fc = 0.5f * (c1 + 1.0f);
    const float pref = fc * NORM * __builtin_amdgcn_rcpf(r);

    // sin(n*pi*x) by Chebyshev recurrence: s_{n+1} = 2*cos(pi*x)*s_n - s_{n-1}
    float b[8];
    {
        float sm1 = 0.0f, sn = s1;
        const float twoc = 2.0f * c1;
        #pragma unroll
        for (int n = 0; n < 8; ++n) {
            b[n] = pref * sn;
            const float nxt = twoc * sn - sm1;
            sm1 = sn; sn = nxt;
        }
    }

    // out flat (l,p,n) = l*P*8 + p*8 + n  ->  f32x4 slot (l*P+p)*2 + {0,1}
    float xl = 1.0f;
    #pragma unroll
    for (int l = 0; l < 4; ++l) {
        const long long base = 2LL * (1LL*l*P + p);
        f32x4 lo = { b[0]*xl, b[1]*xl, b[2]*xl, b[3]*xl };
        f32x4 hi = { b[4]*xl, b[5]*xl, b[6]*xl, b[7]*xl };
        out4[base + 0] = lo;
        out4[base + 1] = hi;
        xl *= x;
    }
}

__global__ __launch_bounds__(256) void ve_sparse2(
    const float* __restrict__ positions,        // [N,3] fp32
    const float* __restrict__ cells,            // [S,3,3] fp32
    const int* __restrict__ cell_shifts,        // [P,3]
    const int* __restrict__ pairs,              // [P,2]
    const int* __restrict__ structure_pairs,    // [P]
    const int* __restrict__ structure_offsets,  // [S]
    f32x4* __restrict__ out4,                   // [4,P,8] fp32 (pre-zeroed)
    int P)
{
    const int T = gridDim.x * blockDim.x;       // threads; each covers 2 pairs
    const int nPairHalf = (P + 1) >> 1;

    #pragma unroll 2
    for (int g = blockIdx.x * blockDim.x + threadIdx.x; g < nPairHalf; g += T) {
        const int p0 = 2 * g;                   // consecutive pair indices p0, p0+1
        // Vectorized pair-stream loads (5 instrs per 2 pairs):
        const int4 pr2 = ((const int4*)pairs)[g];            // pairs[p0], pairs[p0+1]
        const int2 sp2 = ((const int2*)structure_pairs)[g];  // s for both
        const int2 sh0 = ((const int2*)cell_shifts)[3*g + 0];// p0: sx, sy
        const int2 sh1 = ((const int2*)cell_shifts)[3*g + 1];// p0: sz | p1: sx
        const int2 sh2 = ((const int2*)cell_shifts)[3*g + 2];// p1: sy, sz

        ve_one(positions, cells, structure_offsets, out4, P,
               p0, sp2.x, pr2.x, pr2.y, sh0.x, sh0.y, sh1.x);
        if (p0 + 1 < P)
            ve_one(positions, cells, structure_offsets, out4, P,
                   p0 + 1, sp2.y, pr2.z, pr2.w, sh1.y, sh2.x, sh2.y);
    }
}

extern "C" void kernel_launch(void* const* d_in, const int* in_sizes, int n_in,
                              void* d_out, int out_size, void* d_ws, size_t ws_size,
                              hipStream_t stream) {
    const float* positions         = (const float*)d_in[0];
    const float* cells             = (const float*)d_in[1];
    const int*   cell_shifts       = (const int*)d_in[3];
    const int*   pairs             = (const int*)d_in[5];
    const int*   structure_pairs   = (const int*)d_in[7];
    const int*   structure_offsets = (const int*)d_in[8];

    const int P = in_sizes[7];          // structure_pairs is [P]
    const int block = 256;

    const int n4 = out_size / 16;       // out_size = 4*P*8*4 bytes, /16 = f32x4 slots
    fill_zero<<<1024, block, 0, stream>>>((f32x4*)d_out, n4);

    ve_sparse2<<<2048, block, 0, stream>>>(
        positions, cells, cell_shifts, pairs,
        structure_pairs, structure_offsets, (f32x4*)d_out, P);
}